// Round 1
// 566.720 us; speedup vs baseline: 1.0042x; 1.0042x over previous
//
#include <hip/hip_runtime.h>
#include <math.h>

#define BB 32
#define HH 12
#define CC 512
#define DD 768
#define MM 8
#define NER 6
#define NCLS 97
#define KTOT 1542   // 2*D + NER
#define OFFS 1
#define KCH 193     // K-chunk for head/tail GEMM (8*193 = 1544 >= 1542)

// ---------------------------------------------------------------------------
// ws layout (float offsets) — everything written fresh every call (poison-safe),
// no memsets, no atomics anywhere:
//   rawp    [B*H*C]    @ 0         per-(b,h) ht_att partials (plain stores)
//   Sb      [B]        @ 196608
//   rs_part [B*16*D]   @ 196640
//   rs      [B*D]      @ 589856
//   hs      [B*D]      @ 614432
//   accp    [8*2*B*D]  @ 639008    per-kt head/tail GEMM partials
//   fbuf    [2*B*D]    @ 1032224   tanh'd hs_f / ts_f
// total 1081376 floats = 4.33 MB
// ---------------------------------------------------------------------------

// per-(b,h) attention partials: grid (B,H), block 512 (one thread per c).
// rawp[b,h,c] = (sum_m a0)(sum_m a1) / (M*M*H); h-reduction happens downstream.
__global__ void k_att(const float* __restrict__ att, const int* __restrict__ epos,
                      float* __restrict__ rawp) {
    int b = blockIdx.x, h = blockIdx.y;
    __shared__ int pos[16];
    if (threadIdx.x < 16) pos[threadIdx.x] = epos[b * 16 + threadIdx.x] + OFFS;
    __syncthreads();
    int c = threadIdx.x;
    const float* base = att + ((size_t)(b * HH + h)) * CC * CC;
    float a0 = 0.f, a1 = 0.f;
#pragma unroll
    for (int m = 0; m < MM; m++) {
        a0 += base[(size_t)pos[m] * CC + c];
        a1 += base[(size_t)pos[MM + m] * CC + c];
    }
    rawp[((size_t)(b * HH + h)) * CC + c] = a0 * a1 * (1.0f / (MM * MM * HH));
}

// rs partials: grid (B,16), block 192; thread owns 4 d's (float4), loops 32 c.
// First reduces the 12 h-partials for its 32 c's into LDS.
// Blocks with cc==0 also reduce S_b = sum_{h,c} rawp[b,h,c].
__global__ void k_rs_part(const float* __restrict__ seq, const float* __restrict__ rawp,
                          float* __restrict__ rs_part, float* __restrict__ Sb) {
    int b = blockIdx.x, cc = blockIdx.y, t = threadIdx.x;
    __shared__ float wsm[32];
    if (t < 32) {
        float s = 0.f;
#pragma unroll
        for (int h = 0; h < HH; h++)
            s += rawp[((size_t)(b * HH + h)) * CC + cc * 32 + t];
        wsm[t] = s;
    }
    __syncthreads();
    float4 acc = {0.f, 0.f, 0.f, 0.f};
    const float* sp = seq + ((size_t)b * CC + cc * 32) * DD + t * 4;
#pragma unroll 4
    for (int ci = 0; ci < 32; ci++) {
        float w = wsm[ci];
        float4 v = *(const float4*)(sp + (size_t)ci * DD);
        acc.x += v.x * w; acc.y += v.y * w; acc.z += v.z * w; acc.w += v.w * w;
    }
    *(float4*)&rs_part[((size_t)(b * 16 + cc)) * DD + t * 4] = acc;
    if (cc == 0) {
        __shared__ float sb[192];
        float s = 0.f;
        const float* rp = rawp + (size_t)b * HH * CC;
        for (int i = t; i < HH * CC; i += 192) s += rp[i];
        sb[t] = s;
        __syncthreads();
        if (t == 0) {
            float tot = 0.f;
            for (int i = 0; i < 192; i++) tot += sb[i];
            Sb[b] = tot;
        }
    }
}

// finalize rs (divide by S_b + 1e-5) and compute hs = logsumexp over M rows.
// grid B, block 192 (float4 per thread).
__global__ void k_rs_hs(const float* __restrict__ seq, const int* __restrict__ epos,
                        const float* __restrict__ rs_part, const float* __restrict__ Sb,
                        float* __restrict__ rs, float* __restrict__ hs) {
    int b = blockIdx.x, t = threadIdx.x;
    __shared__ int pos[MM];
    if (t < MM) pos[t] = epos[b * 16 + t] + OFFS;   // e = 0 rows only
    __syncthreads();
    float4 acc = {0.f, 0.f, 0.f, 0.f};
    for (int cc = 0; cc < 16; cc++) {
        float4 p = *(const float4*)&rs_part[((size_t)(b * 16 + cc)) * DD + t * 4];
        acc.x += p.x; acc.y += p.y; acc.z += p.z; acc.w += p.w;
    }
    float inv = 1.0f / (Sb[b] + 1e-5f);
    float4 r = {acc.x * inv, acc.y * inv, acc.z * inv, acc.w * inv};
    *(float4*)&rs[b * DD + t * 4] = r;

    float xs0[MM], xs1[MM], xs2[MM], xs3[MM];
#pragma unroll
    for (int m = 0; m < MM; m++) {
        float4 v = *(const float4*)&seq[((size_t)b * CC + pos[m]) * DD + t * 4];
        xs0[m] = v.x; xs1[m] = v.y; xs2[m] = v.z; xs3[m] = v.w;
    }
    float o[4];
    float* xs[4] = {xs0, xs1, xs2, xs3};
#pragma unroll
    for (int comp = 0; comp < 4; comp++) {
        float mx = xs[comp][0];
#pragma unroll
        for (int m = 1; m < MM; m++) mx = fmaxf(mx, xs[comp][m]);
        float se = 0.f;
#pragma unroll
        for (int m = 0; m < MM; m++) se += expf(xs[comp][m] - mx);
        o[comp] = logf(se) + mx;
    }
    float4 hv = {o[0], o[1], o[2], o[3]};
    *(float4*)&hs[b * DD + t * 4] = hv;
}

// head/tail GEMM partials: grid (kt=8, jt=12, e=2), block 256.
// Stages A[b, k-chunk] in LDS (stride 193 -> conflict-free across b lanes).
// Each thread owns (b, 8 consecutive j); plain-stores its partial dot into
// accp[kt] — no atomics, no zero-init needed; k_tanh reduces the 8 partials.
__global__ void k_headtail(const float* __restrict__ hs, const float* __restrict__ rs,
                           const float* __restrict__ ner, const float* __restrict__ Wh,
                           const float* __restrict__ Wt, float* __restrict__ accp) {
    int kt = blockIdx.x, jt = blockIdx.y, e = blockIdx.z;
    int kstart = kt * KCH;
    int klen = min(KCH, KTOT - kstart);
    __shared__ float A[32][KCH];
    for (int i = threadIdx.x; i < 32 * KCH; i += 256) {
        int bb = i / KCH, kk = i - bb * KCH;
        int k = kstart + kk;
        float v = 0.f;
        if (k < KTOT) {
            if (k < DD) v = hs[bb * DD + k];
            else if (k < 2 * DD) v = rs[bb * DD + (k - DD)];
            else v = ner[(bb * 2 + e) * NER + (k - 2 * DD)];
        }
        A[bb][kk] = v;
    }
    __syncthreads();
    int b = threadIdx.x & 31, jq = threadIdx.x >> 5;
    int j0 = jt * 64 + jq * 8;
    const float* W = e ? Wt : Wh;
    const float* Wb = W + (size_t)j0 * KTOT + kstart;
    float acc[8] = {0.f, 0.f, 0.f, 0.f, 0.f, 0.f, 0.f, 0.f};
#pragma unroll 4
    for (int kk = 0; kk < klen; kk++) {
        float a = A[b][kk];
#pragma unroll
        for (int jj = 0; jj < 8; jj++) acc[jj] += a * Wb[(size_t)jj * KTOT + kk];
    }
    float* outp = accp + (((size_t)(kt * 2 + e)) * BB + b) * DD + j0;
#pragma unroll
    for (int jj = 0; jj < 8; jj++) outp[jj] = acc[jj];
}

// reduce the 8 kt-partials + bias + tanh: 2*B*D = 49152 elements, grid 192.
__global__ void k_tanh(const float* __restrict__ accp, const float* __restrict__ bh,
                       const float* __restrict__ bt, float* __restrict__ fbuf) {
    int x = blockIdx.x * 256 + threadIdx.x;
    int e = x / (BB * DD);
    int r = x - e * (BB * DD);
    int j = r % DD;
    float s = e ? bt[j] : bh[j];
#pragma unroll
    for (int kt = 0; kt < 8; kt++) s += accp[(size_t)kt * (2 * BB * DD) + x];
    fbuf[x] = tanhf(s);
}

// bilinear + final matmul: grid NCLS, block 256 (32 b x 8 k-groups).
// logits[b,n] = sum_{f,i,j} hsf[b,f*8+i] * tsf[b,f*8+j] * W[n, f*64+i*8+j] + bias
__global__ void k_bil(const float* __restrict__ fbuf, const float* __restrict__ Wb,
                      const float* __restrict__ bbil, float* __restrict__ out) {
    int n = blockIdx.x;
    int g = threadIdx.x & 7, b = threadIdx.x >> 3;
    const float* hsf = fbuf + b * DD;
    const float* tsf = fbuf + (32 + b) * DD;
    const float* W = Wb + (size_t)n * (DD * 8);
    float acc = 0.f;
    for (int t = 0; t < 12; t++) {
        int f = g + 8 * t;
        float4 h0 = *(const float4*)&hsf[f * 8];
        float4 h1 = *(const float4*)&hsf[f * 8 + 4];
        float4 t0 = *(const float4*)&tsf[f * 8];
        float4 t1 = *(const float4*)&tsf[f * 8 + 4];
        float hv[8] = {h0.x, h0.y, h0.z, h0.w, h1.x, h1.y, h1.z, h1.w};
        float tv[8] = {t0.x, t0.y, t0.z, t0.w, t1.x, t1.y, t1.z, t1.w};
        const float* wf = W + f * 64;
#pragma unroll
        for (int i = 0; i < 8; i++) {
            float4 w0 = *(const float4*)&wf[i * 8];
            float4 w1 = *(const float4*)&wf[i * 8 + 4];
            float dot = tv[0] * w0.x + tv[1] * w0.y + tv[2] * w0.z + tv[3] * w0.w
                      + tv[4] * w1.x + tv[5] * w1.y + tv[6] * w1.z + tv[7] * w1.w;
            acc += hv[i] * dot;
        }
    }
    __shared__ float part[32 * 9];
    part[b * 9 + g] = acc;
    __syncthreads();
    if (g == 0) {
        float s = 0.f;
#pragma unroll
        for (int i = 0; i < 8; i++) s += part[b * 9 + i];
        out[b * NCLS + n] = s + bbil[n];
    }
}

extern "C" void kernel_launch(void* const* d_in, const int* in_sizes, int n_in,
                              void* d_out, int out_size, void* d_ws, size_t ws_size,
                              hipStream_t stream) {
    const float* seq  = (const float*)d_in[0];
    const float* att  = (const float*)d_in[1];
    const float* ner  = (const float*)d_in[2];
    const float* Wh   = (const float*)d_in[3];
    const float* bh   = (const float*)d_in[4];
    const float* Wt   = (const float*)d_in[5];
    const float* bt   = (const float*)d_in[6];
    const float* Wbil = (const float*)d_in[7];
    const float* bbil = (const float*)d_in[8];
    const int*   epos = (const int*)d_in[9];
    float* out = (float*)d_out;
    float* ws = (float*)d_ws;

    float* rawp    = ws;
    float* Sb      = ws + 196608;
    float* rs_part = ws + 196640;
    float* rs      = ws + 589856;
    float* hs      = ws + 614432;
    float* accp    = ws + 639008;
    float* fbuf    = ws + 1032224;

    k_att<<<dim3(BB, HH), 512, 0, stream>>>(att, epos, rawp);
    k_rs_part<<<dim3(BB, 16), 192, 0, stream>>>(seq, rawp, rs_part, Sb);
    k_rs_hs<<<BB, 192, 0, stream>>>(seq, epos, rs_part, Sb, rs, hs);
    k_headtail<<<dim3(8, 12, 2), 256, 0, stream>>>(hs, rs, ner, Wh, Wt, accp);
    k_tanh<<<192, 256, 0, stream>>>(accp, bh, bt, fbuf);
    k_bil<<<NCLS, 256, 0, stream>>>(fbuf, Wbil, bbil, out);
}

// Round 2
// 559.932 us; speedup vs baseline: 1.0163x; 1.0121x over previous
//
#include <hip/hip_runtime.h>
#include <math.h>

#define BB 32
#define HH 12
#define CC 512
#define DD 768
#define MM 8
#define NER 6
#define NCLS 97
#define KTOT 1542   // 2*D + NER
#define OFFS 1
#define KCH 193     // K-chunk for head/tail GEMM (8*193 = 1544 >= 1542)

// ---------------------------------------------------------------------------
// ws layout (float offsets) — everything written fresh every call (poison-safe),
// no memsets, no atomics:
//   Sbp     [B*16]     @ 0        per-(b,cc) partial sums of ht_att
//   rs_part [B*16*D]   @ 512      unnormalized rs partials over c-chunks
//   accp    [8*2*B*D]  @ 393728   per-kt head/tail GEMM partials
//   fbuf    [2*B*D]    @ 786944   tanh'd hs_f / ts_f
// total 836096 floats = 3.34 MB
// 4-kernel chain: k_rs_att -> k_headtail -> k_tanh -> k_bil
// ---------------------------------------------------------------------------

// Fused attention-weights + rs partials: grid (B,16), block 192.
// Phase 1: compute ht_att weights for this block's 32 c's directly from att:
//   w[c] = sum_h (sum_m a0)(sum_m a1) / (M*M*H), via 6 h-groups x 32 c threads.
// Phase 2: thread owns 4 d's (float4), loops 32 c accumulating w*seq.
// Also stores Sbp[b,cc] = sum_c w[c] (plain store; headtail reduces 16).
__global__ void k_rs_att(const float* __restrict__ seq, const float* __restrict__ att,
                         const int* __restrict__ epos, float* __restrict__ rs_part,
                         float* __restrict__ Sbp) {
    int b = blockIdx.x, cc = blockIdx.y, t = threadIdx.x;
    __shared__ int pos16[16];
    __shared__ float part[6][32];
    __shared__ float wsm[32];
    if (t < 16) pos16[t] = epos[b * 16 + t] + OFFS;
    __syncthreads();

    {   // phase 1: t = hg*32 + c, hg in 0..5, handles h = hg and hg+6
        int c = t & 31, hg = t >> 5;
        int cglob = cc * 32 + c;
        float p = 0.f;
        for (int hh = 0; hh < 2; hh++) {
            int h = hg + 6 * hh;
            const float* base = att + ((size_t)(b * HH + h)) * CC * CC + cglob;
            float a0 = 0.f, a1 = 0.f;
#pragma unroll
            for (int m = 0; m < MM; m++) {
                a0 += base[(size_t)pos16[m] * CC];
                a1 += base[(size_t)pos16[MM + m] * CC];
            }
            p += a0 * a1;
        }
        part[hg][c] = p;
    }
    __syncthreads();
    if (t < 32) {
        float w = 0.f;
#pragma unroll
        for (int hg = 0; hg < 6; hg++) w += part[hg][t];
        wsm[t] = w * (1.0f / (MM * MM * HH));
    }
    __syncthreads();
    if (t == 0) {
        float s = 0.f;
#pragma unroll
        for (int c = 0; c < 32; c++) s += wsm[c];
        Sbp[b * 16 + cc] = s;
    }

    // phase 2: weighted sum of seq rows
    float4 acc = {0.f, 0.f, 0.f, 0.f};
    const float* sp = seq + ((size_t)b * CC + cc * 32) * DD + t * 4;
#pragma unroll 4
    for (int ci = 0; ci < 32; ci++) {
        float w = wsm[ci];
        float4 v = *(const float4*)(sp + (size_t)ci * DD);
        acc.x += v.x * w; acc.y += v.y * w; acc.z += v.z * w; acc.w += v.w * w;
    }
    *(float4*)&rs_part[((size_t)(b * 16 + cc)) * DD + t * 4] = acc;
}

// head/tail GEMM with fused A-tile computation: grid (kt=8, jt=12, e=2), block 256.
// A[b,k] computed on the fly:
//   k <  768 : hs[b,k]   = logsumexp_m seq[b, pos0[b,m], k]   (e=0 positions)
//   k < 1536 : rs[b,k-768] = (sum_cc rs_part[b,cc,k-768]) / (Sb+1e-5)
//   k < 1542 : ner[b,e,k-1536]
// LDS stride 193 (odd) -> conflict-free A[b][kk] reads across b lanes.
// Plain-stores partial dots into accp[kt]; k_tanh reduces the 8 partials.
__global__ void k_headtail(const float* __restrict__ seq, const float* __restrict__ rs_part,
                           const float* __restrict__ Sbp, const float* __restrict__ ner,
                           const int* __restrict__ epos, const float* __restrict__ Wh,
                           const float* __restrict__ Wt, float* __restrict__ accp) {
    int kt = blockIdx.x, jt = blockIdx.y, e = blockIdx.z;
    int kstart = kt * KCH;
    int klen = min(KCH, KTOT - kstart);
    __shared__ float A[32][KCH];
    __shared__ int poss[32][MM];
    __shared__ float invS[32];
    int tid = threadIdx.x;
    if (tid < 256) {
        int bb = tid >> 3, m = tid & 7;
        poss[bb][m] = epos[bb * 16 + m] + OFFS;   // e = 0 rows only (hs)
    }
    if (tid < 32) {
        float s = 0.f;
#pragma unroll
        for (int c = 0; c < 16; c++) s += Sbp[tid * 16 + c];
        invS[tid] = 1.0f / (s + 1e-5f);
    }
    __syncthreads();

    for (int i = tid; i < 32 * KCH; i += 256) {
        int bb = i / KCH, kk = i - bb * KCH;
        int k = kstart + kk;
        float v = 0.f;
        if (k < DD) {
            const float* srow = seq + (size_t)bb * CC * DD + k;
            float x[MM];
#pragma unroll
            for (int m = 0; m < MM; m++) x[m] = srow[(size_t)poss[bb][m] * DD];
            float mx = x[0];
#pragma unroll
            for (int m = 1; m < MM; m++) mx = fmaxf(mx, x[m]);
            float se = 0.f;
#pragma unroll
            for (int m = 0; m < MM; m++) se += expf(x[m] - mx);
            v = logf(se) + mx;
        } else if (k < 2 * DD) {
            int d = k - DD;
            float s = 0.f;
#pragma unroll
            for (int c = 0; c < 16; c++) s += rs_part[((size_t)(bb * 16 + c)) * DD + d];
            v = s * invS[bb];
        } else if (k < KTOT) {
            v = ner[(bb * 2 + e) * NER + (k - 2 * DD)];
        }
        A[bb][kk] = v;
    }
    __syncthreads();

    int b = tid & 31, jq = tid >> 5;
    int j0 = jt * 64 + jq * 8;
    const float* W = e ? Wt : Wh;
    const float* Wb = W + (size_t)j0 * KTOT + kstart;
    float acc[8] = {0.f, 0.f, 0.f, 0.f, 0.f, 0.f, 0.f, 0.f};
#pragma unroll 4
    for (int kk = 0; kk < klen; kk++) {
        float a = A[b][kk];
#pragma unroll
        for (int jj = 0; jj < 8; jj++) acc[jj] += a * Wb[(size_t)jj * KTOT + kk];
    }
    float* outp = accp + (((size_t)(kt * 2 + e)) * BB + b) * DD + j0;
#pragma unroll
    for (int jj = 0; jj < 8; jj++) outp[jj] = acc[jj];
}

// reduce the 8 kt-partials + bias + tanh: 2*B*D = 49152 elements, grid 192.
__global__ void k_tanh(const float* __restrict__ accp, const float* __restrict__ bh,
                       const float* __restrict__ bt, float* __restrict__ fbuf) {
    int x = blockIdx.x * 256 + threadIdx.x;
    int e = x / (BB * DD);
    int r = x - e * (BB * DD);
    int j = r % DD;
    float s = e ? bt[j] : bh[j];
#pragma unroll
    for (int kt = 0; kt < 8; kt++) s += accp[(size_t)kt * (2 * BB * DD) + x];
    fbuf[x] = tanhf(s);
}

// bilinear + final matmul: grid NCLS, block 512 (32 b x 16 f-groups).
// logits[b,n] = sum_{f,i,j} hsf[b,f*8+i] * tsf[b,f*8+j] * W[n, f*64+i*8+j] + bias
__global__ void k_bil(const float* __restrict__ fbuf, const float* __restrict__ Wb,
                      const float* __restrict__ bbil, float* __restrict__ out) {
    int n = blockIdx.x;
    int g = threadIdx.x & 15, b = threadIdx.x >> 4;
    const float* hsf = fbuf + b * DD;
    const float* tsf = fbuf + (32 + b) * DD;
    const float* W = Wb + (size_t)n * (DD * 8);
    float acc = 0.f;
    for (int t = 0; t < 6; t++) {
        int f = g + 16 * t;
        float4 h0 = *(const float4*)&hsf[f * 8];
        float4 h1 = *(const float4*)&hsf[f * 8 + 4];
        float4 t0 = *(const float4*)&tsf[f * 8];
        float4 t1 = *(const float4*)&tsf[f * 8 + 4];
        float hv[8] = {h0.x, h0.y, h0.z, h0.w, h1.x, h1.y, h1.z, h1.w};
        float tv[8] = {t0.x, t0.y, t0.z, t0.w, t1.x, t1.y, t1.z, t1.w};
        const float* wf = W + f * 64;
#pragma unroll
        for (int i = 0; i < 8; i++) {
            float4 w0 = *(const float4*)&wf[i * 8];
            float4 w1 = *(const float4*)&wf[i * 8 + 4];
            float dot = tv[0] * w0.x + tv[1] * w0.y + tv[2] * w0.z + tv[3] * w0.w
                      + tv[4] * w1.x + tv[5] * w1.y + tv[6] * w1.z + tv[7] * w1.w;
            acc += hv[i] * dot;
        }
    }
    __shared__ float part[32 * 17];
    part[b * 17 + g] = acc;
    __syncthreads();
    if (g == 0) {
        float s = 0.f;
#pragma unroll
        for (int i = 0; i < 16; i++) s += part[b * 17 + i];
        out[b * NCLS + n] = s + bbil[n];
    }
}

extern "C" void kernel_launch(void* const* d_in, const int* in_sizes, int n_in,
                              void* d_out, int out_size, void* d_ws, size_t ws_size,
                              hipStream_t stream) {
    const float* seq  = (const float*)d_in[0];
    const float* att  = (const float*)d_in[1];
    const float* ner  = (const float*)d_in[2];
    const float* Wh   = (const float*)d_in[3];
    const float* bh   = (const float*)d_in[4];
    const float* Wt   = (const float*)d_in[5];
    const float* bt   = (const float*)d_in[6];
    const float* Wbil = (const float*)d_in[7];
    const float* bbil = (const float*)d_in[8];
    const int*   epos = (const int*)d_in[9];
    float* out = (float*)d_out;
    float* ws = (float*)d_ws;

    float* Sbp     = ws;
    float* rs_part = ws + 512;
    float* accp    = ws + 393728;
    float* fbuf    = ws + 786944;

    k_rs_att<<<dim3(BB, 16), 192, 0, stream>>>(seq, att, epos, rs_part, Sbp);
    k_headtail<<<dim3(8, 12, 2), 256, 0, stream>>>(seq, rs_part, Sbp, ner, epos, Wh, Wt, accp);
    k_tanh<<<192, 256, 0, stream>>>(accp, bh, bt, fbuf);
    k_bil<<<NCLS, 512, 0, stream>>>(fbuf, Wbil, bbil, out);
}

// Round 4
// 559.890 us; speedup vs baseline: 1.0164x; 1.0001x over previous
//
#include <hip/hip_runtime.h>
#include <math.h>

#define BB 32
#define HH 12
#define CC 512
#define DD 768
#define MM 8
#define NER 6
#define NCLS 97
#define KTOT 1542   // 2*D + NER
#define OFFS 1
#define KCH 194     // K-chunk for head/tail GEMM (8*194 = 1552 >= 1542; even -> float2 W loads aligned)

// ---------------------------------------------------------------------------
// ws layout (float offsets) — everything written fresh every call (poison-safe),
// no memsets, no atomics:
//   Sbp     [B*16]     @ 0        per-(b,cc) partial sums of ht_att
//   rs_part [B*16*D]   @ 512      unnormalized rs partials over c-chunks
//   accp    [8*2*B*D]  @ 393728   per-kt head/tail GEMM partials
//   fbuf    [2*B*D]    @ 786944   tanh'd hs_f / ts_f
// total 836096 floats = 3.34 MB
// 4-kernel chain: k_rs_att -> k_headtail -> k_tanh -> k_bil
// ---------------------------------------------------------------------------

// Fused attention-weights + rs partials: grid (B,16), block 384 (6 waves for
// latency hiding; was 192/3 waves -> 1.5 waves/SIMD, latency-exposed gathers).
// Phase 1: 12 h-groups x 32 c threads, ONE h each (16 gathered loads/thread).
// Phase 2: c-loop split in half across thread groups (16 iters each), partials
// combined through LDS. Also stores Sbp[b,cc] = sum_c w[c].
__global__ void k_rs_att(const float* __restrict__ seq, const float* __restrict__ att,
                         const int* __restrict__ epos, float* __restrict__ rs_part,
                         float* __restrict__ Sbp) {
    int b = blockIdx.x, cc = blockIdx.y, t = threadIdx.x;
    __shared__ int pos16[16];
    __shared__ float part[12][32];
    __shared__ float wsm[32];
    __shared__ float4 pacc[2][192];
    if (t < 16) pos16[t] = epos[b * 16 + t] + OFFS;
    __syncthreads();

    {   // phase 1: t = h*32 + c, h in 0..11
        int c = t & 31, h = t >> 5;
        int cglob = cc * 32 + c;
        const float* base = att + ((size_t)(b * HH + h)) * CC * CC + cglob;
        float a0 = 0.f, a1 = 0.f;
#pragma unroll
        for (int m = 0; m < MM; m++) {
            a0 += base[(size_t)pos16[m] * CC];
            a1 += base[(size_t)pos16[MM + m] * CC];
        }
        part[h][c] = a0 * a1;
    }
    __syncthreads();
    if (t < 32) {
        float w = 0.f;
#pragma unroll
        for (int h = 0; h < 12; h++) w += part[h][t];
        wsm[t] = w * (1.0f / (MM * MM * HH));
    }
    __syncthreads();
    if (t == 0) {
        float s = 0.f;
#pragma unroll
        for (int c = 0; c < 32; c++) s += wsm[c];
        Sbp[b * 16 + cc] = s;
    }

    // phase 2: weighted sum of seq rows; half = which 16-c subchunk
    int half = t / 192, tt = t - half * 192;
    float4 acc = {0.f, 0.f, 0.f, 0.f};
    const float* sp = seq + ((size_t)b * CC + cc * 32 + half * 16) * DD + tt * 4;
    const float* wp = wsm + half * 16;
#pragma unroll 4
    for (int ci = 0; ci < 16; ci++) {
        float w = wp[ci];
        float4 v = *(const float4*)(sp + (size_t)ci * DD);
        acc.x += v.x * w; acc.y += v.y * w; acc.z += v.z * w; acc.w += v.w * w;
    }
    pacc[half][tt] = acc;
    __syncthreads();
    if (t < 192) {
        float4 p0 = pacc[0][t], p1 = pacc[1][t];
        float4 r = {p0.x + p1.x, p0.y + p1.y, p0.z + p1.z, p0.w + p1.w};
        *(float4*)&rs_part[((size_t)(b * 16 + cc)) * DD + t * 4] = r;
    }
}

// head/tail GEMM with fused A-tile computation: grid (kt=8, jt=12, e=2), block 256.
// A[b,k] computed on the fly:
//   k <  768 : hs[b,k]   = logsumexp_m seq[b, pos0[b,m], k]   (e=0 positions)
//   k < 1536 : rs[b,k-768] = (sum_cc rs_part[b,cc,k-768]) / (Sb+1e-5)
//   k < 1542 : ner[b,e,k-1536]
// LDS stride 195 (odd) -> conflict-free A[b][kk] reads across b lanes.
// W read as float2 (KCH even + j0 mult-of-8 + row stride 6168%8==0 -> aligned),
// halving W load-instruction count. Plain-stores partials into accp[kt].
__global__ void k_headtail(const float* __restrict__ seq, const float* __restrict__ rs_part,
                           const float* __restrict__ Sbp, const float* __restrict__ ner,
                           const int* __restrict__ epos, const float* __restrict__ Wh,
                           const float* __restrict__ Wt, float* __restrict__ accp) {
    int kt = blockIdx.x, jt = blockIdx.y, e = blockIdx.z;
    int kstart = kt * KCH;
    int klen = min(KCH, KTOT - kstart);   // 194 or 184 (kt=7); always even
    __shared__ float A[32][KCH + 1];
    __shared__ int poss[32][MM];
    __shared__ float invS[32];
    int tid = threadIdx.x;
    {
        int bb = tid >> 3, m = tid & 7;
        poss[bb][m] = epos[bb * 16 + m] + OFFS;   // e = 0 rows only (hs)
    }
    if (tid < 32) {
        float s = 0.f;
#pragma unroll
        for (int c = 0; c < 16; c++) s += Sbp[tid * 16 + c];
        invS[tid] = 1.0f / (s + 1e-5f);
    }
    __syncthreads();

    for (int i = tid; i < 32 * KCH; i += 256) {
        int bb = i / KCH, kk = i - bb * KCH;
        int k = kstart + kk;
        float v = 0.f;
        if (k < DD) {
            const float* srow = seq + (size_t)bb * CC * DD + k;
            float x[MM];
#pragma unroll
            for (int m = 0; m < MM; m++) x[m] = srow[(size_t)poss[bb][m] * DD];
            float mx = x[0];
#pragma unroll
            for (int m = 1; m < MM; m++) mx = fmaxf(mx, x[m]);
            float se = 0.f;
#pragma unroll
            for (int m = 0; m < MM; m++) se += expf(x[m] - mx);
            v = logf(se) + mx;
        } else if (k < 2 * DD) {
            int d = k - DD;
            float s = 0.f;
#pragma unroll
            for (int c = 0; c < 16; c++) s += rs_part[((size_t)(bb * 16 + c)) * DD + d];
            v = s * invS[bb];
        } else if (k < KTOT) {
            v = ner[(bb * 2 + e) * NER + (k - 2 * DD)];
        }
        A[bb][kk] = v;
    }
    __syncthreads();

    int b = tid & 31, jq = tid >> 5;
    int j0 = jt * 64 + jq * 8;
    const float* W = e ? Wt : Wh;
    const float* Wb = W + (size_t)j0 * KTOT + kstart;
    float acc[8] = {0.f, 0.f, 0.f, 0.f, 0.f, 0.f, 0.f, 0.f};
#pragma unroll 4
    for (int kk = 0; kk < klen; kk += 2) {
        float a0 = A[b][kk], a1 = A[b][kk + 1];
#pragma unroll
        for (int jj = 0; jj < 8; jj++) {
            float2 w = *(const float2*)&Wb[(size_t)jj * KTOT + kk];
            acc[jj] += a0 * w.x + a1 * w.y;
        }
    }
    float* outp = accp + (((size_t)(kt * 2 + e)) * BB + b) * DD + j0;
#pragma unroll
    for (int jj = 0; jj < 8; jj++) outp[jj] = acc[jj];
}

// reduce the 8 kt-partials + bias + tanh: 2*B*D = 49152 elements, grid 192.
__global__ void k_tanh(const float* __restrict__ accp, const float* __restrict__ bh,
                       const float* __restrict__ bt, float* __restrict__ fbuf) {
    int x = blockIdx.x * 256 + threadIdx.x;
    int e = x / (BB * DD);
    int r = x - e * (BB * DD);
    int j = r % DD;
    float s = e ? bt[j] : bh[j];
#pragma unroll
    for (int kt = 0; kt < 8; kt++) s += accp[(size_t)kt * (2 * BB * DD) + x];
    fbuf[x] = tanhf(s);
}

// bilinear + final matmul: grid NCLS, block 512 (32 b x 16 f-groups).
// logits[b,n] = sum_{f,i,j} hsf[b,f*8+i] * tsf[b,f*8+j] * W[n, f*64+i*8+j] + bias
__global__ void k_bil(const float* __restrict__ fbuf, const float* __restrict__ Wb,
                      const float* __restrict__ bbil, float* __restrict__ out) {
    int n = blockIdx.x;
    int g = threadIdx.x & 15, b = threadIdx.x >> 4;
    const float* hsf = fbuf + b * DD;
    const float* tsf = fbuf + (32 + b) * DD;
    const float* W = Wb + (size_t)n * (DD * 8);
    float acc = 0.f;
    for (int t = 0; t < 6; t++) {
        int f = g + 16 * t;
        float4 h0 = *(const float4*)&hsf[f * 8];
        float4 h1 = *(const float4*)&hsf[f * 8 + 4];
        float4 t0 = *(const float4*)&tsf[f * 8];
        float4 t1 = *(const float4*)&tsf[f * 8 + 4];
        float hv[8] = {h0.x, h0.y, h0.z, h0.w, h1.x, h1.y, h1.z, h1.w};
        float tv[8] = {t0.x, t0.y, t0.z, t0.w, t1.x, t1.y, t1.z, t1.w};
        const float* wf = W + f * 64;
#pragma unroll
        for (int i = 0; i < 8; i++) {
            float4 w0 = *(const float4*)&wf[i * 8];
            float4 w1 = *(const float4*)&wf[i * 8 + 4];
            float dot = tv[0] * w0.x + tv[1] * w0.y + tv[2] * w0.z + tv[3] * w0.w
                      + tv[4] * w1.x + tv[5] * w1.y + tv[6] * w1.z + tv[7] * w1.w;
            acc += hv[i] * dot;
        }
    }
    __shared__ float part[32 * 17];
    part[b * 17 + g] = acc;
    __syncthreads();
    if (g == 0) {
        float s = 0.f;
#pragma unroll
        for (int i = 0; i < 16; i++) s += part[b * 17 + i];
        out[b * NCLS + n] = s + bbil[n];
    }
}

extern "C" void kernel_launch(void* const* d_in, const int* in_sizes, int n_in,
                              void* d_out, int out_size, void* d_ws, size_t ws_size,
                              hipStream_t stream) {
    const float* seq  = (const float*)d_in[0];
    const float* att  = (const float*)d_in[1];
    const float* ner  = (const float*)d_in[2];
    const float* Wh   = (const float*)d_in[3];
    const float* bh   = (const float*)d_in[4];
    const float* Wt   = (const float*)d_in[5];
    const float* bt   = (const float*)d_in[6];
    const float* Wbil = (const float*)d_in[7];
    const float* bbil = (const float*)d_in[8];
    const int*   epos = (const int*)d_in[9];
    float* out = (float*)d_out;
    float* ws = (float*)d_ws;

    float* Sbp     = ws;
    float* rs_part = ws + 512;
    float* accp    = ws + 393728;
    float* fbuf    = ws + 786944;

    k_rs_att<<<dim3(BB, 16), 384, 0, stream>>>(seq, att, epos, rs_part, Sbp);
    k_headtail<<<dim3(8, 12, 2), 256, 0, stream>>>(seq, rs_part, Sbp, ner, epos, Wh, Wt, accp);
    k_tanh<<<192, 256, 0, stream>>>(accp, bh, bt, fbuf);
    k_bil<<<NCLS, 512, 0, stream>>>(fbuf, Wbil, bbil, out);
}